// Round 11
// baseline (13870.430 us; speedup 1.0000x reference)
//
#include <hip/hip_runtime.h>
#include <stdint.h>

#define NCU 256
#define TPB 512
#define IN_DIM 1024
#define HID1   1024
#define HID2   2048
#define T_STEPS 2048

// LL exchange (r10, proven): {payload,tag} 8-B pairs inside ONE 64-B sector.
// 8-B store = single transaction -> tag visible <=> payload visible.
// lines1: 4 pairs (h1). lines2: 8 pairs (h2). 64-B stride, 4 buffers deep.
#define LINE_DW 16

typedef float    f32x4 __attribute__((ext_vector_type(4)));
typedef uint32_t u32x4 __attribute__((ext_vector_type(4)));
typedef uint32_t u32x2 __attribute__((ext_vector_type(2)));
typedef __fp16   h16x2 __attribute__((ext_vector_type(2)));

__device__ __forceinline__ uint32_t pkh(float a, float b){
  h16x2 h = __builtin_amdgcn_cvt_pkrtz(a, b);
  uint32_t u; __builtin_memcpy(&u, &h, 4); return u;
}
__device__ __forceinline__ uint32_t pkhu(uint32_t a, uint32_t b){
  return pkh(__uint_as_float(a), __uint_as_float(b));
}

#if __has_builtin(__builtin_amdgcn_fdot2)
__device__ __forceinline__ float fdot2_(uint32_t w, uint32_t h, float c){
  h16x2 wf, hf; __builtin_memcpy(&wf, &w, 4); __builtin_memcpy(&hf, &h, 4);
  return __builtin_amdgcn_fdot2(wf, hf, c, false);
}
#else
__device__ __forceinline__ float fdot2_(uint32_t w, uint32_t h, float c){
  h16x2 wf, hf; __builtin_memcpy(&wf, &w, 4); __builtin_memcpy(&hf, &h, 4);
  c = fmaf((float)wf[0], (float)hf[0], c);
  return fmaf((float)wf[1], (float)hf[1], c);
}
#endif

__device__ __forceinline__ float dot16(u32x4 w, u32x4 h, float c){
  c = fdot2_(w[0], h[0], c); c = fdot2_(w[1], h[1], c);
  c = fdot2_(w[2], h[2], c); c = fdot2_(w[3], h[3], c);
  return c;
}

__device__ __forceinline__ float wave_reduce(float v){
  v += __shfl_xor(v, 32); v += __shfl_xor(v, 16); v += __shfl_xor(v, 8);
  v += __shfl_xor(v, 4);  v += __shfl_xor(v, 2);  v += __shfl_xor(v, 1);
  return v;
}

__device__ __forceinline__ float sigm_(float x){
  return __builtin_amdgcn_rcpf(1.f + __expf(-x));
}
__device__ __forceinline__ float tanh_(float x){
  float e = __expf(2.f * x);
  return (e - 1.f) * __builtin_amdgcn_rcpf(e + 1.f);
}

__global__ void prep_kernel(uint32_t* __restrict__ lines)
{
  int idx = blockIdx.x * blockDim.x + threadIdx.x;
  const int total = 2 * 4 * NCU * LINE_DW;
  for (int i = idx; i < total; i += gridDim.x * blockDim.x)
    __hip_atomic_store(lines + i, 0u, __ATOMIC_RELAXED, __HIP_MEMORY_SCOPE_AGENT);
}

// ---------------------------------------------------------------------------
// persistent 2-layer LSTM. 256 blocks x 512 threads (8 waves).
// Block b owns layer1 units [4b,4b+4), layer2 units [8b,8b+8).
// Iteration t:
//  seg1: waves0-1: phase A (16 L1 rows, 8 lanes/row, rotated granules)
//        waves2-7: phase B (32 L2 rows, stride-6)            -> S1
//  seg2: wave0: gates1 + publish h1[t]
//        wave1: gates2 + publish h2[t-2] + partial_out
//        waves4-7: combined poll+gather h1[t] & h2[t-2]      -> S2
// 2 barriers/step, ONE exposed RT window (both lines in flight together).
// ---------------------------------------------------------------------------
__global__ __launch_bounds__(TPB, 1) void lstm_persist(
    const float* __restrict__ x,    const float* __restrict__ Wih1,
    const float* __restrict__ Whh1, const float* __restrict__ b1,
    const float* __restrict__ Wih2, const float* __restrict__ Whh2,
    const float* __restrict__ b2,   const float* __restrict__ Wout,
    uint32_t* __restrict__ lines,   float* __restrict__ partial_out)
{
  __shared__ u32x4 whh2_u4[32 * 256];   // 128 KiB f16 Whh2 (granules)
  __shared__ u32x4 h1g[2][128];         // h1 f16, double-buffered
  __shared__ u32x4 h2g[256];            // h2 f16
  __shared__ float gsum1[16], gx1v[16], gsum2[32], b2v[32];

  uint32_t* lines1 = lines;
  uint32_t* lines2 = lines + 4 * NCU * LINE_DW;

  const int b    = blockIdx.x;
  const int tid  = threadIdx.x;
  const int lane = tid & 63;
  const int wv   = tid >> 6;

  // ---- init: Whh2 slice -> LDS f16 granules ----
  for (int i = tid; i < 32 * 256; i += TPB) {
    int lr = i >> 8, u = i & 255;
    int g = lr >> 3, uu2 = lr & 7;
    const f32x4* s4 = (const f32x4*)(Whh2 + (int64_t)(g * HID2 + 8 * b + uu2) * HID2);
    f32x4 lo = s4[2 * u], hi = s4[2 * u + 1];
    u32x4 wv4;
    wv4[0] = pkh(lo[0], lo[1]); wv4[1] = pkh(lo[2], lo[3]);
    wv4[2] = pkh(hi[0], hi[1]); wv4[3] = pkh(hi[2], hi[3]);
    whh2_u4[i] = wv4;
  }

  // ---- waves 0-1: Whh1 (16 rows, 8 lanes/row, 128 elem/lane) in regs ----
  // w1h4[m] holds granule s*16 + ((m+2s)&15) of the row (rotation kills the
  // stride-256B LDS bank conflict in phase A).
  u32x4 w1h4[16];
  if (wv < 2) {
    const int r = wv * 8 + (lane >> 3);   // 0..15 = 4*gate+unit
    const int s = lane & 7;
    const int g = r >> 2, u = r & 3;
    const float* wrow = Whh1 + (int64_t)(g * HID1 + 4 * b + u) * IN_DIM;
    #pragma unroll
    for (int m = 0; m < 16; ++m) {
      int gi = (m + 2 * s) & 15;
      const float* e = wrow + s * 128 + gi * 8;
      u32x4 wv4;
      wv4[0] = pkh(e[0], e[1]); wv4[1] = pkh(e[2], e[3]);
      wv4[2] = pkh(e[4], e[5]); wv4[3] = pkh(e[6], e[7]);
      w1h4[m] = wv4;
    }
  }

  // ---- waves 2-7: Wih2 rows lr=(wv-2)+6k in regs ----
  u32x4 wi_reg[6][2];
  #pragma unroll
  for (int k = 0; k < 6; ++k) {
    int lr = (wv - 2) + 6 * k;
    if (wv >= 2 && lr < 32) {
      int g = lr >> 3, uu = lr & 7;
      const f32x4* s4 = (const f32x4*)(Wih2 + (int64_t)(g * HID2 + 8 * b + uu) * IN_DIM);
      #pragma unroll
      for (int q = 0; q < 2; ++q) {
        int u = lane + 64 * q;
        f32x4 lo = s4[2 * u], hi = s4[2 * u + 1];
        u32x4 wv4;
        wv4[0] = pkh(lo[0], lo[1]); wv4[1] = pkh(lo[2], lo[3]);
        wv4[2] = pkh(hi[0], hi[1]); wv4[3] = pkh(hi[2], hi[3]);
        wi_reg[k][q] = wv4;
      }
    }
  }

  // ---- gx1 = Wih1 @ x + b1 (constant over t) ----
  #pragma unroll
  for (int rr = 0; rr < 2; ++rr) {
    int lr1 = wv * 2 + rr;
    int g = lr1 >> 2, uu = lr1 & 3;
    int row = g * HID1 + 4 * b + uu;
    float s = 0.f;
    #pragma unroll
    for (int j = 0; j < 16; ++j)
      s += Wih1[(int64_t)row * IN_DIM + lane + 64 * j] * x[lane + 64 * j];
    s = wave_reduce(s);
    if (lane == 0) gx1v[lr1] = s + b1[row];
  }
  if (tid < 32) { int g = tid >> 3, uu = tid & 7; b2v[tid] = b2[g * HID2 + 8 * b + uu]; }
  {
    uint32_t* p1 = (uint32_t*)h1g;
    uint32_t* p2 = (uint32_t*)h2g;
    for (int i = tid; i < 2 * 128 * 4; i += TPB) p1[i] = 0u;
    for (int i = tid; i < 256 * 4;     i += TPB) p2[i] = 0u;
  }

  const float woutreg = Wout[8 * b + (lane & 7)];
  float c1reg = 0.f, c2reg = 0.f;
  __syncthreads();

  // ---- time loop ----
  for (int t = 0; t < T_STEPS + 2; ++t) {
    // ======== seg1: phase A (waves0-1) || phase B (waves2-7) ========
    if (wv < 2) {
      if (t < T_STEPS) {
        const u32x4* h1A = h1g[(t + 1) & 1];
        const int s = lane & 7;
        float v = 0.f;
        #pragma unroll
        for (int m = 0; m < 16; ++m) {
          int gi = s * 16 + ((m + 2 * s) & 15);
          v = dot16(w1h4[m], h1A[gi], v);
        }
        v += __shfl_xor(v, 1); v += __shfl_xor(v, 2); v += __shfl_xor(v, 4);
        if (s == 0) gsum1[wv * 8 + (lane >> 3)] = v;
      }
    } else if (t >= 2) {
      const u32x4* h1B = h1g[t & 1];
      u32x4 x1a = h1B[lane], x1b = h1B[64 + lane];
      u32x4 x20 = h2g[lane],       x21 = h2g[64 + lane];
      u32x4 x22 = h2g[128 + lane], x23 = h2g[192 + lane];
      #pragma unroll
      for (int k = 0; k < 6; ++k) {
        const int lr = (wv - 2) + 6 * k;
        if (lr < 32) {
          float s = dot16(wi_reg[k][0], x1a, 0.f);
          s = dot16(wi_reg[k][1], x1b, s);
          s = dot16(whh2_u4[lr * 256 + lane],       x20, s);
          s = dot16(whh2_u4[lr * 256 + 64 + lane],  x21, s);
          s = dot16(whh2_u4[lr * 256 + 128 + lane], x22, s);
          s = dot16(whh2_u4[lr * 256 + 192 + lane], x23, s);
          s = wave_reduce(s);
          if (lane == 0) gsum2[lr] = s;
        }
      }
    }
    __syncthreads();   // S1: gsum1, gsum2 ready

    // ======== seg2: gates+publish (waves0,1) || gather (waves4-7) ========
    if (wv == 0) {
      if (t < T_STEPS) {
        const int u1 = lane & 3;
        float gi = sigm_(gsum1[u1]      + gx1v[u1]);
        float gf = sigm_(gsum1[4 + u1]  + gx1v[4 + u1]);
        float gg = tanh_(gsum1[8 + u1]  + gx1v[8 + u1]);
        float go = sigm_(gsum1[12 + u1] + gx1v[12 + u1]);
        c1reg = gf * c1reg + gi * gg;
        float h1v = go * tanh_(c1reg);
        if (lane < 4) {
          uint32_t* p = lines1 + ((size_t)(t & 3) * NCU + b) * LINE_DW + 2 * lane;
          u32x2 st; st[0] = __float_as_uint(h1v); st[1] = (uint32_t)(t + 1);
          asm volatile("global_store_dwordx2 %0, %1, off sc0 sc1"
                       :: "v"(p), "v"(st) : "memory");
        }
      }
    } else if (wv == 1) {
      if (t >= 2) {
        const int u2 = lane & 7;
        float gi = sigm_(gsum2[u2]      + b2v[u2]);
        float gf = sigm_(gsum2[8 + u2]  + b2v[8 + u2]);
        float gg = tanh_(gsum2[16 + u2] + b2v[16 + u2]);
        float go = sigm_(gsum2[24 + u2] + b2v[24 + u2]);
        c2reg = gf * c2reg + gi * gg;
        float h2v = go * tanh_(c2reg);
        if (t <= T_STEPS && lane < 8) {
          uint32_t* p = lines2 + ((size_t)(t & 3) * NCU + b) * LINE_DW + 2 * lane;
          u32x2 st; st[0] = __float_as_uint(h2v); st[1] = (uint32_t)(t + 1);
          asm volatile("global_store_dwordx2 %0, %1, off sc0 sc1"
                       :: "v"(p), "v"(st) : "memory");
        }
        float contrib = (lane < 8) ? h2v * woutreg : 0.f;
        float po = wave_reduce(contrib);
        if (lane == 0) partial_out[(int64_t)(t - 2) * NCU + b] = po;
      }
    } else if (wv >= 4) {
      const int j = tid - NCU;             // 0..255
      const uint32_t tg = (uint32_t)(t + 1);
      bool done1 = !(t < T_STEPS);
      bool done2 = !(t >= 2 && t <= T_STEPS);
      const uint32_t* l1 = lines1 + ((size_t)(t & 3) * NCU + j) * LINE_DW;
      const uint32_t* l2 = lines2 + ((size_t)(t & 3) * NCU + j) * LINE_DW;
      while (!done1 || !done2) {
        u32x4 a0, a1, d0, d1, d2, d3;
        if (!done1) {
          asm volatile("global_load_dwordx4 %0, %1, off sc0 sc1"
                       : "=&v"(a0) : "v"(l1));
          asm volatile("global_load_dwordx4 %0, %1, off offset:16 sc0 sc1"
                       : "=&v"(a1) : "v"(l1));
        }
        if (!done2) {
          asm volatile("global_load_dwordx4 %0, %1, off sc0 sc1"
                       : "=&v"(d0) : "v"(l2));
          asm volatile("global_load_dwordx4 %0, %1, off offset:16 sc0 sc1"
                       : "=&v"(d1) : "v"(l2));
          asm volatile("global_load_dwordx4 %0, %1, off offset:32 sc0 sc1"
                       : "=&v"(d2) : "v"(l2));
          asm volatile("global_load_dwordx4 %0, %1, off offset:48 sc0 sc1"
                       : "=&v"(d3) : "v"(l2));
        }
        asm volatile("s_waitcnt vmcnt(0)" ::: "memory");
        if (!done1 && a0[1] == tg && a0[3] == tg && a1[1] == tg && a1[3] == tg) {
          u32x2 hp; hp[0] = pkhu(a0[0], a0[2]); hp[1] = pkhu(a1[0], a1[2]);
          ((u32x2*)h1g[t & 1])[j] = hp;    // becomes h1[t]
          done1 = true;
        }
        if (!done2 && d0[1] == tg && d0[3] == tg && d1[1] == tg && d1[3] == tg &&
            d2[1] == tg && d2[3] == tg && d3[1] == tg && d3[3] == tg) {
          u32x4 hp;
          hp[0] = pkhu(d0[0], d0[2]); hp[1] = pkhu(d1[0], d1[2]);
          hp[2] = pkhu(d2[0], d2[2]); hp[3] = pkhu(d3[0], d3[2]);
          h2g[j] = hp;                     // becomes h2[t-2]
          done2 = true;
        }
        if (!done1 || !done2) __builtin_amdgcn_s_sleep(1);
      }
    }
    __syncthreads();   // S2
  }
}

// ---------------------------------------------------------------------------
__global__ void out_reduce(const float* __restrict__ partial_out,
                           const float* __restrict__ bout,
                           float* __restrict__ out)
{
  int t = blockIdx.x;
  int lane = threadIdx.x;   // 64 threads
  float s = 0.f;
  #pragma unroll
  for (int q = 0; q < 4; ++q) s += partial_out[(int64_t)t * NCU + lane + 64 * q];
  s = wave_reduce(s);
  if (lane == 0) out[t] = s + bout[0];
}

extern "C" void kernel_launch(void* const* d_in, const int* in_sizes, int n_in,
                              void* d_out, int out_size, void* d_ws, size_t ws_size,
                              hipStream_t stream)
{
  const float* x    = (const float*)d_in[0];
  const float* Wih1 = (const float*)d_in[1];
  const float* Whh1 = (const float*)d_in[2];
  const float* b1   = (const float*)d_in[3];
  const float* Wih2 = (const float*)d_in[4];
  const float* Whh2 = (const float*)d_in[5];
  const float* b2   = (const float*)d_in[6];
  const float* Wout = (const float*)d_in[7];
  const float* bout = (const float*)d_in[8];
  float* out = (float*)d_out;

  char* ws = (char*)d_ws;
  size_t off = 0;
  auto take = [&](size_t bytes) -> char* {
    char* p = ws + off;
    off = (off + bytes + 255) & ~(size_t)255;
    return p;
  };
  uint32_t* lines    = (uint32_t*)take((size_t)2 * 4 * NCU * LINE_DW * 4); // 128 KB
  float* partial_out = (float*)take((size_t)T_STEPS * NCU * 4);            // 2 MB

  if (off > ws_size) return;

  hipLaunchKernelGGL(prep_kernel, dim3(32), dim3(256), 0, stream, lines);

  void* args[] = { &x, &Wih1, &Whh1, &b1, &Wih2, &Whh2, &b2, &Wout,
                   &lines, &partial_out };
  (void)hipLaunchCooperativeKernel((void*)lstm_persist, dim3(NCU), dim3(TPB),
                                   args, 0, stream);

  hipLaunchKernelGGL(out_reduce, dim3(T_STEPS), dim3(64), 0, stream,
                     partial_out, bout, out);
}